// Round 8
// baseline (327.862 us; speedup 1.0000x reference)
//
#include <hip/hip_runtime.h>
#include <stdint.h>

// Problem constants: B=8, S=4096, H=1024, E=8 -> N = 32768 tokens.
#define HDIM 1024
#define NEXP 8
#define NTOK 32768
#define BM 256
#define BN 128
#define BK 32
#define NSLOT 3

typedef __attribute__((ext_vector_type(4))) float f32x4;
typedef __attribute__((ext_vector_type(8))) short bf16x8;

// fp32 -> bf16 bits, round-to-nearest-even
__device__ __forceinline__ unsigned short f2bf(float f) {
  union { float f; unsigned u; } v; v.f = f;
  unsigned r = v.u + 0x7FFF + ((v.u >> 16) & 1);
  return (unsigned short)(r >> 16);
}

// async global->LDS, 16B per lane. LDS dest must be wave-uniform base + lane*16.
__device__ __forceinline__ void gload_lds16(const void* g, void* l) {
  __builtin_amdgcn_global_load_lds(
      (__attribute__((address_space(1))) void*)(g),
      (__attribute__((address_space(3))) void*)(l), 16, 0, 0);
}

// ---------------------------------------------------------------------------
// Kernel 1: router (fp32 exact) + x -> bf16 conversion, one streaming pass.
// R8: barrier-free stream. WgT (transposed Wg, 32 KB) lives in LDS; each
// thread owns rows {16i + (t>>5)} x float-cols 4*(t&31)..+4 (same coalesced
// float4 x-reads / uint2 xb-writes as before), FMAs against WgT[e][k] b128
// reads (4-way bank conflict, hidden under the 128 FMA/chunk), and partial
// logits reduce over the 32 lanes sharing a row via __shfl_xor tree.
// No per-chunk barriers at all (old version: 16 barriers + 8-way-conflicted
// tile[lane][..] reads). fp32 math; only summation grouping differs.
// ---------------------------------------------------------------------------
__global__ __launch_bounds__(512) void router_convert(
    const float* __restrict__ x, const float* __restrict__ Wg,
    const float* __restrict__ bg, unsigned short* __restrict__ xb,
    float* __restrict__ p) {
  __shared__ float WgT[NEXP][HDIM];  // 32 KB, WgT[e][k] = Wg[k][e]
  const int t = threadIdx.x;
  const int c4 = t & 31;       // float4 column within the 128-float chunk
  const int rh = t >> 5;       // 0..15 -> rows i*16 + rh
  const int tok0 = blockIdx.x * 64;

  // one-time transpose preload (coalesced global read; scatter LDS write)
#pragma unroll
  for (int i = 0; i < 16; ++i) {
    const int idx = i * 512 + t;
    WgT[idx & 7][idx >> 3] = Wg[idx];
  }
  __syncthreads();

  float acc[4][NEXP] = {};
  float4 v[4], vn[4];
#pragma unroll
  for (int i = 0; i < 4; ++i)
    v[i] = *(const float4*)(x + (size_t)(tok0 + i * 16 + rh) * HDIM + c4 * 4);

  for (int ck = 0; ck < 8; ++ck) {
    if (ck < 7) {  // register prefetch: next chunk flies under this compute
#pragma unroll
      for (int i = 0; i < 4; ++i)
        vn[i] = *(const float4*)(x + (size_t)(tok0 + i * 16 + rh) * HDIM +
                                 (ck + 1) * 128 + c4 * 4);
    }
#pragma unroll
    for (int i = 0; i < 4; ++i) {  // bf16 convert + coalesced store
      const size_t goff = (size_t)(tok0 + i * 16 + rh) * HDIM + ck * 128 + c4 * 4;
      union { unsigned short us[4]; uint2 u2; } pk;
      pk.us[0] = f2bf(v[i].x); pk.us[1] = f2bf(v[i].y);
      pk.us[2] = f2bf(v[i].z); pk.us[3] = f2bf(v[i].w);
      *(uint2*)(xb + goff) = pk.u2;
    }
#pragma unroll
    for (int e = 0; e < NEXP; ++e) {
      const f32x4 w4 = *(const f32x4*)(&WgT[e][ck * 128 + c4 * 4]);
#pragma unroll
      for (int i = 0; i < 4; ++i)
        acc[i][e] += v[i].x * w4[0] + v[i].y * w4[1] +
                     v[i].z * w4[2] + v[i].w * w4[3];
    }
#pragma unroll
    for (int i = 0; i < 4; ++i) v[i] = vn[i];
  }

  // reduce over the 32 lanes (c4) sharing each row; masks <=16 stay in-half
#pragma unroll
  for (int i = 0; i < 4; ++i)
#pragma unroll
    for (int e = 0; e < NEXP; ++e) {
      float s = acc[i][e];
#pragma unroll
      for (int m = 16; m >= 1; m >>= 1) s += __shfl_xor(s, m);
      acc[i][e] = s;
    }

  if (c4 == 0) {
#pragma unroll
    for (int i = 0; i < 4; ++i) {
      float l[NEXP];
#pragma unroll
      for (int e = 0; e < NEXP; ++e) l[e] = acc[i][e] + bg[e];
      float mx = l[0];
#pragma unroll
      for (int e = 1; e < NEXP; ++e) mx = fmaxf(mx, l[e]);
      float s = 0.f;
#pragma unroll
      for (int e = 0; e < NEXP; ++e) s += __expf(l[e] - mx);
      p[tok0 + i * 16 + rh] = 1.0f / s;  // softmax prob of argmax = exp(0)/sum
    }
  }
}

// ---------------------------------------------------------------------------
// Kernel 2: We [k][n] fp32 -> Wt [n][k] bf16 (transpose + convert). Unchanged.
// ---------------------------------------------------------------------------
__global__ __launch_bounds__(256) void transpose_convert(
    const float* __restrict__ We, unsigned short* __restrict__ wt) {
  __shared__ float tile[64][65];
  const int bj = blockIdx.x, bi = blockIdx.y;
  const int tx = threadIdx.x & 63, ty = threadIdx.x >> 6;
#pragma unroll
  for (int i = 0; i < 16; ++i) {
    int row = i * 4 + ty;
    tile[row][tx] = We[(size_t)(bi * 64 + row) * HDIM + bj * 64 + tx];
  }
  __syncthreads();
#pragma unroll
  for (int i = 0; i < 16; ++i) {
    int row = i * 4 + ty;
    wt[(size_t)(bj * 64 + row) * HDIM + bi * 64 + tx] = f2bf(tile[tx][row]);
  }
}

// ---------------------------------------------------------------------------
// Kernel 3: C[m][n] = (A[m][:] @ We[:][n] + be[n]) * p[m], bf16 MFMA.
// R8: 2-blocks/CU deep pipeline. BM=256 BN=128 BK=32, NSLOT=3 -> 72 KB LDS
// -> 2 blocks/CU (16 waves, was 1 block in R7): the other block fills every
// barrier bubble. ONE barrier per K-tile (was 4 in R7):
//   {vmcnt(3); s_barrier; 8x ds_read_b128; issue 3 gload_lds (tile it+2);
//    setprio(1); 16 MFMA; setprio(0)}
// WAR proof: a wave's ds_reads of slot it%3 complete before its MFMAs issue
// (compiler lgkm waits), hence before its next barrier; staging of slot
// (it+2)%3 only starts after that barrier -> no second barrier needed.
// vmcnt: 3 loads/thread/tile; entry vmcnt(3) => tile it fully landed for ALL
// waves after the barrier (each waited its own 3 oldest); tile it+1 stays in
// flight ACROSS the barrier (T4, never drain to 0 mid-loop).
// BK=32 rank-3 swizzle: stored slot s of row r holds k-granule s^((r>>1)&3);
// frag read slot = q^((col>>1)&3) -> quad 4(col&1)+q^((col>>1)&3): 8 distinct
// quads per 8 lanes (enumerated), 2 lanes/quad over 16 -> conflict-free.
// Source XOR stays within the row's 64 B chunk -> coalescing preserved.
// ---------------------------------------------------------------------------
__global__ __launch_bounds__(512, 4) void moe_gemm(
    const unsigned short* __restrict__ A, const unsigned short* __restrict__ Bt,
    const float* __restrict__ be, const float* __restrict__ p,
    float* __restrict__ out) {
  __shared__ __align__(16) unsigned short As[NSLOT][BM * BK];  // 3 x 16 KB
  __shared__ __align__(16) unsigned short Bs[NSLOT][BN * BK];  // 3 x 8 KB
  const int t = threadIdx.x;

  const unsigned lin = blockIdx.x;            // 1024 blocks
  const unsigned xcd = lin & 7, idx = lin >> 3;
  const int n0 = (int)(idx & 7) * BN;          // 8 n-blocks inner
  const int m0 = (int)(xcd * 16 + (idx >> 3)) * BM;  // 16 m-panels per XCD

  // staging: A 1024 granules (2/thread), B 512 (1/thread).
  // granule c: row = c>>2, s = c&3; source k-granule = s ^ ((row>>1)&3).
  const unsigned short* ga0;
  const unsigned short* ga1;
  const unsigned short* gb0;
  {
    const int r0 = t >> 2, s0 = t & 3;
    ga0 = A + (size_t)(m0 + r0) * HDIM + (s0 ^ ((r0 >> 1) & 3)) * 8;
    const int c1 = t + 512;
    const int r1 = c1 >> 2, s1 = c1 & 3;
    ga1 = A + (size_t)(m0 + r1) * HDIM + (s1 ^ ((r1 >> 1) & 3)) * 8;
    gb0 = Bt + (size_t)(n0 + r0) * HDIM + (s0 ^ ((r0 >> 1) & 3)) * 8;
  }

  const int lane = t & 63, wid = t >> 6;
  const int wm = (wid >> 1) * 64, wn = (wid & 1) * 64;  // 4M x 2N wave grid
  const int col = lane & 15, q = lane >> 4;  // frag: row=col, k=q*8+i
  const int sl = q ^ ((col >> 1) & 3);       // swizzled slot

  int offA[4], offB[4];  // shorts within a slot: granule = row*4 + sl
#pragma unroll
  for (int i = 0; i < 4; ++i) {
    offA[i] = ((wm + i * 16 + col) * 4 + sl) * 8;
    offB[i] = ((wn + i * 16 + col) * 4 + sl) * 8;
  }

  f32x4 acc[4][4] = {};

  auto stage = [&](int sslot) {
    gload_lds16(ga0, &As[sslot][(size_t)t * 8]);
    gload_lds16(ga1, &As[sslot][(size_t)(t + 512) * 8]);
    gload_lds16(gb0, &Bs[sslot][(size_t)t * 8]);
    ga0 += BK; ga1 += BK; gb0 += BK;
  };

  // prologue: tiles 0,1 in flight (6 loads/thread)
  stage(0);
  stage(1);

  int slot = 0;
  const int NT = HDIM / BK;  // 32
  for (int it = 0; it < NT; ++it) {
    if (it < NT - 1)
      asm volatile("s_waitcnt vmcnt(3)" ::: "memory");  // tile it landed
    else
      asm volatile("s_waitcnt vmcnt(0)" ::: "memory");  // final drain
    __builtin_amdgcn_s_barrier();

    bf16x8 a[4], b[4];
#pragma unroll
    for (int i = 0; i < 4; ++i) {
      a[i] = *(const bf16x8*)(&As[slot][offA[i]]);
      b[i] = *(const bf16x8*)(&Bs[slot][offB[i]]);
    }
    int s2 = slot + 2; if (s2 >= NSLOT) s2 -= NSLOT;
    if (it < NT - 2) stage(s2);  // issue overlaps the lgkm wait below

    __builtin_amdgcn_s_setprio(1);
#pragma unroll
    for (int i = 0; i < 4; ++i)
#pragma unroll
      for (int j = 0; j < 4; ++j)
        acc[i][j] = __builtin_amdgcn_mfma_f32_16x16x32_bf16(a[i], b[j],
                                                            acc[i][j], 0, 0, 0);
    __builtin_amdgcn_s_setprio(0);

    slot = slot + 1; if (slot >= NSLOT) slot = 0;
  }

  // epilogue: C/D layout col = lane&15 (n), row = q*4 + r (m)  [m89/m91]
  float pv[4][4];
#pragma unroll
  for (int i = 0; i < 4; ++i)
#pragma unroll
    for (int r = 0; r < 4; ++r) pv[i][r] = p[m0 + wm + i * 16 + q * 4 + r];
#pragma unroll
  for (int j = 0; j < 4; ++j) {
    const int n = n0 + wn + j * 16 + col;
    const float bev = be[n];
#pragma unroll
    for (int i = 0; i < 4; ++i) {
#pragma unroll
      for (int r = 0; r < 4; ++r) {
        const int m = m0 + wm + i * 16 + q * 4 + r;
        out[(size_t)m * HDIM + n] = (acc[i][j][r] + bev) * pv[i][r];
      }
    }
  }
}

// ---------------------------------------------------------------------------
extern "C" void kernel_launch(void* const* d_in, const int* in_sizes, int n_in,
                              void* d_out, int out_size, void* d_ws, size_t ws_size,
                              hipStream_t stream) {
  const float* x  = (const float*)d_in[0];
  const float* Wg = (const float*)d_in[1];
  const float* bg = (const float*)d_in[2];
  const float* We = (const float*)d_in[3];
  const float* be = (const float*)d_in[4];
  float* out = (float*)d_out;

  // workspace layout (needs 69,337,088 B):
  char* ws = (char*)d_ws;
  unsigned short* xb = (unsigned short*)ws;                         // 67,108,864 B
  unsigned short* wt = (unsigned short*)(ws + (size_t)67108864);    //  2,097,152 B
  float* p = (float*)(ws + (size_t)67108864 + 2097152);             //    131,072 B

  router_convert<<<NTOK / 64, 512, 0, stream>>>(x, Wg, bg, xb, p);
  transpose_convert<<<dim3(16, 16), 256, 0, stream>>>(We, wt);
  moe_gemm<<<(NTOK / BM) * (HDIM / BN), 512, 0, stream>>>(xb, wt, be, p, out);
}